// Round 10
// baseline (350.181 us; speedup 1.0000x reference)
//
#include <hip/hip_runtime.h>
#include <math.h>

// Problem constants
#define NTHETA  360
#define NLAMBDA 720
#define MMAX    361
#define NROWS   2880                       /* 8 heads * 360 theta rows */
#define ANGD (6.283185307179586476925286766559 / 720.0)  /* 2*pi/720 */

// DFT tiling
#define MT 128          /* m-tile per block (3 tiles cover 384 >= 361)   */
#define RT 64           /* row-tile per block (45 tiles cover 2880)      */
#define JC 36           /* j chunk staged in LDS (divides 720/S, mult 4) */
#define MPAD 384        /* padded m extent of cos table / partials       */

// Workspace: Tc[720][384] | P[S][384][2880] | outT[2][361][8][360]
#define TC_ELEMS   ((size_t)720 * MPAD)            /* 276,480 floats   */
#define P_STRIDE   ((size_t)MPAD * NROWS)          /* 1,105,920 floats */
#define OUTT_ELEMS ((size_t)MMAX * 8 * NTHETA)     /* 1,039,680 floats */

// ---------------------------------------------------------------------------
// Cos table: Tc[j*384+mp] = (2pi/720)*cos(2pi*(j*mp mod 720)/720), 0 for mp>=361.
// ---------------------------------------------------------------------------
__global__ __launch_bounds__(256) void tw_init_kernel(float* __restrict__ Tc) {
    int i = blockIdx.x * 256 + threadIdx.x;
    if (i >= (int)TC_ELEMS) return;
    int j = i / MPAD, mp = i % MPAD;
    float v = 0.f;
    if (mp < MMAX) {
        int p = (j * mp) % 720;                      // exact integer phase
        v = (float)ANGD * cosf((float)(ANGD * (double)p));
    }
    Tc[i] = v;
}

// ---------------------------------------------------------------------------
// Real DFT as register-tiled GEMM (x and Tc both LDS-staged):
//   P[s][mp][row] = sum_{j in split s} x[row][j] * Tc[j][mp]
// grid (3 mtile, 45 rtile, S), block 256 = (tm 16)x(tr 16); thread: 8m x 4r accs.
// ---------------------------------------------------------------------------
__global__ __launch_bounds__(256) void dft_re_kernel(
    const float* __restrict__ x, const float* __restrict__ Tc,
    float* __restrict__ P, int S) {
    const int mt  = blockIdx.x;
    const int rt  = blockIdx.y;
    const int s   = blockIdx.z;
    const int tid = threadIdx.x;
    const int tm  = tid & 15;
    const int tr  = tid >> 4;
    const int m0g = mt * MT;            // block m base (global)
    const int mo  = tm * 8;             // thread m offset in tile
    const int rb  = rt * RT;            // block row base
    const int tr4 = tr * 4;             // thread row offset
    const int jlen = 720 / S;
    const int j0   = s * jlen;

    __shared__ __align__(16) float tc[JC][MT + 4];   // 19 KB
    __shared__ float xs[JC][65];                     // 9.2 KB, [j][row] pitch 65

    float acc[8][4];
#pragma unroll
    for (int a = 0; a < 8; ++a)
#pragma unroll
        for (int b = 0; b < 4; ++b) acc[a][b] = 0.f;

    for (int jc = 0; jc < jlen; jc += JC) {
        __syncthreads();
        for (int i = tid; i < JC * MT; i += 256) {
            int jj = i >> 7;            // /128
            int mm = i & (MT - 1);
            tc[jj][mm] = Tc[(size_t)(j0 + jc + jj) * MPAD + m0g + mm];
        }
        for (int i = tid; i < JC * RT; i += 256) {
            int jj = i % JC;            // fast -> coalesced within x rows
            int rr = i / JC;
            xs[jj][rr] = x[(size_t)(rb + rr) * 720 + j0 + jc + jj];
        }
        __syncthreads();

        for (int jb = 0; jb < JC; jb += 4) {
#pragma unroll
            for (int u = 0; u < 4; ++u) {
                float4 ta = *(const float4*)&tc[jb + u][mo];
                float4 tb = *(const float4*)&tc[jb + u][mo + 4];
                float xr0 = xs[jb + u][tr4 + 0];
                float xr1 = xs[jb + u][tr4 + 1];
                float xr2 = xs[jb + u][tr4 + 2];
                float xr3 = xs[jb + u][tr4 + 3];
#pragma unroll
                for (int i = 0; i < 4; ++i) {
                    float xe = (i == 0) ? xr0 : (i == 1) ? xr1 : (i == 2) ? xr2 : xr3;
                    acc[0][i] += ta.x * xe;
                    acc[1][i] += ta.y * xe;
                    acc[2][i] += ta.z * xe;
                    acc[3][i] += ta.w * xe;
                    acc[4][i] += tb.x * xe;
                    acc[5][i] += tb.y * xe;
                    acc[6][i] += tb.z * xe;
                    acc[7][i] += tb.w * xe;
                }
            }
        }
    }

#pragma unroll
    for (int mi = 0; mi < 8; ++mi) {
        float* dst = P + ((size_t)s * MPAD + m0g + mo + mi) * NROWS + rb + tr4;
        *(float4*)dst = make_float4(acc[mi][0], acc[mi][1], acc[mi][2], acc[mi][3]);
    }
}

// ---------------------------------------------------------------------------
// Sum j-split partials into P[0]
// ---------------------------------------------------------------------------
__global__ __launch_bounds__(256) void reduce_kernel(float* __restrict__ P, int S) {
    size_t i = ((size_t)blockIdx.x * 256 + threadIdx.x) * 4;
    if (i >= P_STRIDE) return;
    float4 a = *(float4*)&P[i];
    for (int s = 1; s < S; ++s) {
        float4 b = *(const float4*)&P[(size_t)s * P_STRIDE + i];
        a.x += b.x; a.y += b.y; a.z += b.z; a.w += b.w;
    }
    *(float4*)&P[i] = a;
}

// ---------------------------------------------------------------------------
// Contraction (real part), k-split x2, depth-2 register pipeline on W stream:
//   outT[ks][m][h][n] = sum_{k in half ks} P0[m][h*360+k] * W[m][n][k]
// grid (6 nch, 361 m, 2 ks), block 128, launch_bounds(128,1) to free VGPRs.
// thread: n = nch*64 + tid/2, cg = tid&1 -> heads cg*4..+3. 45 float4 of W per
// thread in 9 chunks of 5; A/B buffers refilled while the other computes.
// ---------------------------------------------------------------------------
__global__ __launch_bounds__(128, 1) void contract_re_kernel(
    const float* __restrict__ W, const float* __restrict__ P0,
    float* __restrict__ outT) {
    const int nch = blockIdx.x;
    const int m   = blockIdx.y;
    const int ks  = blockIdx.z;
    const int tid = threadIdx.x;

    __shared__ __align__(16) float xl[8 * 180];       // 5.76 KB
    for (int i4 = tid; i4 < 360; i4 += 128) {         // 360 float4 stages
        int h = i4 / 45, kk4 = i4 % 45;
        *(float4*)&xl[h * 180 + kk4 * 4] =
            *(const float4*)&P0[(size_t)m * NROWS + h * 360 + ks * 180 + kk4 * 4];
    }
    __syncthreads();

    const int n  = nch * 64 + (tid >> 1);
    const int cg = tid & 1;
    if (n >= NTHETA) return;          // guard: 6*64=384 > 360 (restored in R10)

    const float4* wp = (const float4*)(W + ((size_t)m * 360 + n) * 360 + ks * 180);
    const float*  xb = xl + cg * 4 * 180;

    float a0 = 0.f, a1 = 0.f, a2 = 0.f, a3 = 0.f;
    float4 A[5], B[5];
#pragma unroll
    for (int q = 0; q < 5; ++q) A[q] = wp[q];
#pragma unroll
    for (int q = 0; q < 5; ++q) B[q] = wp[5 + q];

#define CHUNK_FMA(BUF, c)                                                  \
    {                                                                      \
        _Pragma("unroll")                                                  \
        for (int q = 0; q < 5; ++q) {                                      \
            const int kk = (c) * 20 + q * 4;                               \
            float4 v0 = *(const float4*)(xb + 0 * 180 + kk);               \
            float4 v1 = *(const float4*)(xb + 1 * 180 + kk);               \
            float4 v2 = *(const float4*)(xb + 2 * 180 + kk);               \
            float4 v3 = *(const float4*)(xb + 3 * 180 + kk);               \
            a0 += BUF[q].x * v0.x + BUF[q].y * v0.y + BUF[q].z * v0.z + BUF[q].w * v0.w; \
            a1 += BUF[q].x * v1.x + BUF[q].y * v1.y + BUF[q].z * v1.z + BUF[q].w * v1.w; \
            a2 += BUF[q].x * v2.x + BUF[q].y * v2.y + BUF[q].z * v2.z + BUF[q].w * v2.w; \
            a3 += BUF[q].x * v3.x + BUF[q].y * v3.y + BUF[q].z * v3.z + BUF[q].w * v3.w; \
        }                                                                  \
    }

#pragma unroll
    for (int cc = 0; cc < 4; ++cc) {
        CHUNK_FMA(A, 2 * cc);
        {
            const int ci = (2 * cc + 2 <= 8) ? (2 * cc + 2) : 8;
#pragma unroll
            for (int q = 0; q < 5; ++q) A[q] = wp[ci * 5 + q];
        }
        CHUNK_FMA(B, 2 * cc + 1);
        {
            const int ci = (2 * cc + 3 <= 8) ? (2 * cc + 3) : 8;
#pragma unroll
            for (int q = 0; q < 5; ++q) B[q] = wp[ci * 5 + q];
        }
    }
    CHUNK_FMA(A, 8);
#undef CHUNK_FMA

    float av[4] = {a0, a1, a2, a3};
    float* oT = outT + (size_t)ks * OUTT_ELEMS;
#pragma unroll
    for (int i = 0; i < 4; ++i) {
        int h = cg * 4 + i;
        oT[((size_t)m * 8 + h) * 360 + n] = av[i];    // coalesced along n
    }
}

// ---------------------------------------------------------------------------
// Transpose + k-split sum: out[h][n][m] = outT[0][m][h][n] + outT[1][m][h][n]
// grid (12 mt, 12 nt, 8 h), block (32, 8).
// ---------------------------------------------------------------------------
__global__ __launch_bounds__(256) void transpose_kernel(
    const float* __restrict__ outT, float* __restrict__ out, long long out_elems) {
    __shared__ float t[32][33];
    const int mt = blockIdx.x, nt = blockIdx.y, h = blockIdx.z;
    const int cx = threadIdx.x, cy = threadIdx.y;

#pragma unroll
    for (int ri = 0; ri < 4; ++ri) {
        int r = cy + ri * 8;                 // m offset in tile
        int mm = mt * 32 + r, nn = nt * 32 + cx;
        float v = 0.f;
        if (mm < MMAX && nn < NTHETA) {
            size_t idx = ((size_t)mm * 8 + h) * 360 + nn;
            v = outT[idx] + outT[OUTT_ELEMS + idx];
        }
        t[r][cx] = v;
    }
    __syncthreads();
#pragma unroll
    for (int ri = 0; ri < 4; ++ri) {
        int r = cy + ri * 8;                 // n offset in tile
        int nn = nt * 32 + r, mm = mt * 32 + cx;
        if (mm < MMAX && nn < NTHETA) {
            size_t oidx = ((size_t)(h * 360) + nn) * 361 + mm;
            if (oidx < (size_t)out_elems) out[oidx] = t[cx][r];
        }
    }
}

// ---------------------------------------------------------------------------
// Fallback: fused, exact integer-phase double trig. Real-only or complex out.
// ---------------------------------------------------------------------------
__global__ __launch_bounds__(256) void fused_kernel(
    const float* __restrict__ x, const float* __restrict__ W,
    float* __restrict__ out, long long nx, long long nw, long long out_elems,
    int complexOut) {
    const int m   = blockIdx.x;
    const int tid = threadIdx.x;

    __shared__ float xl[16 * 360];

    for (int row = tid; row < NROWS; row += 256) {    // row = h*360 + k
        int h = row / 360, k = row % 360;
        const size_t base = (size_t)row * 720;
        float ar = 0.f, ai = 0.f;
        if (base + 720 <= (size_t)nx) {
            const float* xr = x + base;
            for (int j = 0; j < 720; ++j) {
                int p = (j * m) % 720;
                double a = ANGD * (double)p;
                float xe = xr[j];
                ar += xe * (float)(ANGD * cos(a));
                ai -= xe * (float)(ANGD * sin(a));
            }
        }
        xl[(h * 2) * 360 + k]     = ar;
        xl[(h * 2 + 1) * 360 + k] = ai;
    }
    __syncthreads();

    for (int n = tid; n < 360; n += 256) {
        float accr[8], acci[8];
#pragma unroll
        for (int i = 0; i < 8; ++i) { accr[i] = 0.f; acci[i] = 0.f; }
        const size_t wbase = ((size_t)m * 360 + n) * 360;
        if (wbase + 360 <= (size_t)nw) {
            const float* wr = W + wbase;
            for (int k = 0; k < 360; ++k) {
                float w = wr[k];
#pragma unroll
                for (int h = 0; h < 8; ++h) {
                    accr[h] += w * xl[(h * 2) * 360 + k];
                    acci[h] += w * xl[(h * 2 + 1) * 360 + k];
                }
            }
        }
#pragma unroll
        for (int h = 0; h < 8; ++h) {
            size_t e = ((size_t)(h * 360) + n) * 361 + m;
            if (complexOut) {
                if (2 * e + 1 < (size_t)out_elems) {
                    out[2 * e]     = accr[h];
                    out[2 * e + 1] = acci[h];
                }
            } else {
                if (e < (size_t)out_elems) out[e] = accr[h];
            }
        }
    }
}

extern "C" void kernel_launch(void* const* d_in, const int* in_sizes, int n_in,
                              void* d_out, int out_size, void* d_ws, size_t ws_size,
                              hipStream_t stream) {
    if (n_in < 2) return;
    const float* x = (const float*)d_in[0];   // [1,8,360,720] float32
    const float* W = (const float*)d_in[1];   // [361,360,360] float32
    float* out = (float*)d_out;               // float32[out_size]; expected = Re(result)

    const long long nx = in_sizes[0];
    const long long nw = in_sizes[1];
    const long long out_elems = (long long)out_size;
    const bool complexOut = (out_elems >= 2LL * 1039680LL);
    const bool sizesOk = (nx >= 2073600LL) && (nw >= 46785600LL);

    int S = 0;
    for (int c = 4; c >= 1; c >>= 1) {
        size_t need = (TC_ELEMS + (size_t)c * P_STRIDE + 2 * OUTT_ELEMS) * sizeof(float);
        if (ws_size >= need) { S = c; break; }
    }

    if (!complexOut && sizesOk && S > 0 && d_ws != nullptr) {
        float* Tc = (float*)d_ws;
        float* P  = Tc + TC_ELEMS;
        float* oT = P + (size_t)S * P_STRIDE;
        tw_init_kernel<<<(int)((TC_ELEMS + 255) / 256), 256, 0, stream>>>(Tc);
        dft_re_kernel<<<dim3(3, 45, S), 256, 0, stream>>>(x, Tc, P, S);
        if (S > 1)
            reduce_kernel<<<(int)((P_STRIDE / 4 + 255) / 256), 256, 0, stream>>>(P, S);
        contract_re_kernel<<<dim3(6, 361, 2), 128, 0, stream>>>(W, P, oT);
        transpose_kernel<<<dim3(12, 12, 8), dim3(32, 8), 0, stream>>>(oT, out, out_elems);
    } else {
        fused_kernel<<<dim3(361), 256, 0, stream>>>(x, W, out, nx, nw, out_elems,
                                                    complexOut ? 1 : 0);
    }
}

// Round 11
// 332.689 us; speedup vs baseline: 1.0526x; 1.0526x over previous
//
#include <hip/hip_runtime.h>
#include <math.h>

// Problem constants
#define NTHETA  360
#define NLAMBDA 720
#define MMAX    361
#define NROWS   2880                       /* 8 heads * 360 theta rows */
#define ANGD (6.283185307179586476925286766559 / 720.0)  /* 2*pi/720 */

// DFT tiling
#define MT 128
#define RT 64
#define JC 36
#define MPAD 384

// Workspace: Tc[720][384] | P[S][384][2880] | outT[361][8][360]
#define TC_ELEMS   ((size_t)720 * MPAD)            /* 276,480 floats   */
#define P_STRIDE   ((size_t)MPAD * NROWS)          /* 1,105,920 floats */
#define OUTT_ELEMS ((size_t)MMAX * 8 * NTHETA)     /* 1,039,680 floats */

// ---------------------------------------------------------------------------
// Cos table
// ---------------------------------------------------------------------------
__global__ __launch_bounds__(256) void tw_init_kernel(float* __restrict__ Tc) {
    int i = blockIdx.x * 256 + threadIdx.x;
    if (i >= (int)TC_ELEMS) return;
    int j = i / MPAD, mp = i % MPAD;
    float v = 0.f;
    if (mp < MMAX) {
        int p = (j * mp) % 720;
        v = (float)ANGD * cosf((float)(ANGD * (double)p));
    }
    Tc[i] = v;
}

// ---------------------------------------------------------------------------
// Real DFT as register-tiled GEMM (unchanged from R10)
// ---------------------------------------------------------------------------
__global__ __launch_bounds__(256) void dft_re_kernel(
    const float* __restrict__ x, const float* __restrict__ Tc,
    float* __restrict__ P, int S) {
    const int mt  = blockIdx.x;
    const int rt  = blockIdx.y;
    const int s   = blockIdx.z;
    const int tid = threadIdx.x;
    const int tm  = tid & 15;
    const int tr  = tid >> 4;
    const int m0g = mt * MT;
    const int mo  = tm * 8;
    const int rb  = rt * RT;
    const int tr4 = tr * 4;
    const int jlen = 720 / S;
    const int j0   = s * jlen;

    __shared__ __align__(16) float tc[JC][MT + 4];
    __shared__ float xs[JC][65];

    float acc[8][4];
#pragma unroll
    for (int a = 0; a < 8; ++a)
#pragma unroll
        for (int b = 0; b < 4; ++b) acc[a][b] = 0.f;

    for (int jc = 0; jc < jlen; jc += JC) {
        __syncthreads();
        for (int i = tid; i < JC * MT; i += 256) {
            int jj = i >> 7;
            int mm = i & (MT - 1);
            tc[jj][mm] = Tc[(size_t)(j0 + jc + jj) * MPAD + m0g + mm];
        }
        for (int i = tid; i < JC * RT; i += 256) {
            int jj = i % JC;
            int rr = i / JC;
            xs[jj][rr] = x[(size_t)(rb + rr) * 720 + j0 + jc + jj];
        }
        __syncthreads();

        for (int jb = 0; jb < JC; jb += 4) {
#pragma unroll
            for (int u = 0; u < 4; ++u) {
                float4 ta = *(const float4*)&tc[jb + u][mo];
                float4 tb = *(const float4*)&tc[jb + u][mo + 4];
                float xr0 = xs[jb + u][tr4 + 0];
                float xr1 = xs[jb + u][tr4 + 1];
                float xr2 = xs[jb + u][tr4 + 2];
                float xr3 = xs[jb + u][tr4 + 3];
#pragma unroll
                for (int i = 0; i < 4; ++i) {
                    float xe = (i == 0) ? xr0 : (i == 1) ? xr1 : (i == 2) ? xr2 : xr3;
                    acc[0][i] += ta.x * xe;
                    acc[1][i] += ta.y * xe;
                    acc[2][i] += ta.z * xe;
                    acc[3][i] += ta.w * xe;
                    acc[4][i] += tb.x * xe;
                    acc[5][i] += tb.y * xe;
                    acc[6][i] += tb.z * xe;
                    acc[7][i] += tb.w * xe;
                }
            }
        }
    }

#pragma unroll
    for (int mi = 0; mi < 8; ++mi) {
        float* dst = P + ((size_t)s * MPAD + m0g + mo + mi) * NROWS + rb + tr4;
        *(float4*)dst = make_float4(acc[mi][0], acc[mi][1], acc[mi][2], acc[mi][3]);
    }
}

// ---------------------------------------------------------------------------
// Sum j-split partials into P[0]
// ---------------------------------------------------------------------------
__global__ __launch_bounds__(256) void reduce_kernel(float* __restrict__ P, int S) {
    size_t i = ((size_t)blockIdx.x * 256 + threadIdx.x) * 4;
    if (i >= P_STRIDE) return;
    float4 a = *(float4*)&P[i];
    for (int s = 1; s < S; ++s) {
        float4 b = *(const float4*)&P[(size_t)s * P_STRIDE + i];
        a.x += b.x; a.y += b.y; a.z += b.z; a.w += b.w;
    }
    *(float4*)&P[i] = a;
}

// ---------------------------------------------------------------------------
// Contraction, k-coalesced lanes:
//   outT[m][h][n] = sum_k P0[m][h*360+k] * W[m][n][k]
// grid (12 ntile, 361 m), block 128: thread = (np 0..15, q 0..7).
// Thread handles rows na = n0+np, nb = n0+np+16; k-slice = float4 idx q+8s.
// Wave's 64 lanes (8 np x 8 q) -> each W load instr covers 8 rows x 128 B
// contiguous runs: 16 fully-consumed lines (vs 32 lines @16B before).
// x kept in registers per step (8 conflict-free LDS b128), partials over q
// reduced via LDS at the end.
// ---------------------------------------------------------------------------
__global__ __launch_bounds__(128, 1) void contract_re_kernel(
    const float* __restrict__ W, const float* __restrict__ P0,
    float* __restrict__ outT) {
    const int nt  = blockIdx.x;          // 12 tiles of 32 n (last partly masked)
    const int m   = blockIdx.y;
    const int tid = threadIdx.x;
    const int q   = tid & 7;             // k-phase
    const int np  = tid >> 3;            // 0..15

    __shared__ __align__(16) float xs[NROWS];            // 11.5 KB  [h*360+k]
    __shared__ float pl[16 * 2 * 8 * 8];                 // 8 KB partials

    for (int i = tid * 4; i < NROWS; i += 128 * 4)
        *(float4*)&xs[i] = *(const float4*)&P0[(size_t)m * NROWS + i];
    __syncthreads();

    const int n0 = nt * 32;
    int na = n0 + np;      if (na > 359) na = 359;       // clamp (dup read, store masked)
    int nb = n0 + np + 16; if (nb > 359) nb = 359;
    const float4* wa = (const float4*)(W + ((size_t)m * 360 + na) * 360);
    const float4* wb = (const float4*)(W + ((size_t)m * 360 + nb) * 360);

    float acc[2][8];
#pragma unroll
    for (int j = 0; j < 2; ++j)
#pragma unroll
        for (int h = 0; h < 8; ++h) acc[j][h] = 0.f;

    float4 A0 = wa[q], B0 = wb[q];
    for (int s = 0; s < 12; ++s) {
        const int f4 = q + 8 * s;
        if (f4 >= 90) break;
        const int f4n = f4 + 8;
        float4 An = A0, Bn = B0;
        if (f4n < 90) { An = wa[f4n]; Bn = wb[f4n]; }    // prefetch next step

        float4 xv[8];
#pragma unroll
        for (int h = 0; h < 8; ++h)
            xv[h] = *(const float4*)&xs[h * 360 + f4 * 4];
#pragma unroll
        for (int h = 0; h < 8; ++h) {
            acc[0][h] += A0.x * xv[h].x + A0.y * xv[h].y + A0.z * xv[h].z + A0.w * xv[h].w;
            acc[1][h] += B0.x * xv[h].x + B0.y * xv[h].y + B0.z * xv[h].z + B0.w * xv[h].w;
        }
        A0 = An; B0 = Bn;
    }

    // partials: pl[((np*2+j)*8+h)*8+q]
#pragma unroll
    for (int j = 0; j < 2; ++j)
#pragma unroll
        for (int h = 0; h < 8; ++h)
            pl[((np * 2 + j) * 8 + h) * 8 + q] = acc[j][h];
    __syncthreads();

    // reduce over q and store: 256 outputs (32 n x 8 h), 2 per thread
    for (int oi = tid; oi < 256; oi += 128) {
        const int n_loc = oi >> 3;       // 0..31
        const int h     = oi & 7;
        const int npp   = n_loc & 15, j = n_loc >> 4;
        const float* p = &pl[((npp * 2 + j) * 8 + h) * 8];
        float sum = p[0] + p[1] + p[2] + p[3] + p[4] + p[5] + p[6] + p[7];
        const int n = n0 + n_loc;
        if (n < NTHETA)
            outT[((size_t)m * 8 + h) * 360 + n] = sum;
    }
}

// ---------------------------------------------------------------------------
// Transpose outT[m][h][n] -> out[h][n][m]
// ---------------------------------------------------------------------------
__global__ __launch_bounds__(256) void transpose_kernel(
    const float* __restrict__ outT, float* __restrict__ out, long long out_elems) {
    __shared__ float t[32][33];
    const int mt = blockIdx.x, nt = blockIdx.y, h = blockIdx.z;
    const int cx = threadIdx.x, cy = threadIdx.y;

#pragma unroll
    for (int ri = 0; ri < 4; ++ri) {
        int r = cy + ri * 8;
        int mm = mt * 32 + r, nn = nt * 32 + cx;
        float v = 0.f;
        if (mm < MMAX && nn < NTHETA)
            v = outT[((size_t)mm * 8 + h) * 360 + nn];
        t[r][cx] = v;
    }
    __syncthreads();
#pragma unroll
    for (int ri = 0; ri < 4; ++ri) {
        int r = cy + ri * 8;
        int nn = nt * 32 + r, mm = mt * 32 + cx;
        if (mm < MMAX && nn < NTHETA) {
            size_t oidx = ((size_t)(h * 360) + nn) * 361 + mm;
            if (oidx < (size_t)out_elems) out[oidx] = t[cx][r];
        }
    }
}

// ---------------------------------------------------------------------------
// Fallback: fused, exact integer-phase double trig.
// ---------------------------------------------------------------------------
__global__ __launch_bounds__(256) void fused_kernel(
    const float* __restrict__ x, const float* __restrict__ W,
    float* __restrict__ out, long long nx, long long nw, long long out_elems,
    int complexOut) {
    const int m   = blockIdx.x;
    const int tid = threadIdx.x;

    __shared__ float xl[16 * 360];

    for (int row = tid; row < NROWS; row += 256) {
        int h = row / 360, k = row % 360;
        const size_t base = (size_t)row * 720;
        float ar = 0.f, ai = 0.f;
        if (base + 720 <= (size_t)nx) {
            const float* xr = x + base;
            for (int j = 0; j < 720; ++j) {
                int p = (j * m) % 720;
                double a = ANGD * (double)p;
                float xe = xr[j];
                ar += xe * (float)(ANGD * cos(a));
                ai -= xe * (float)(ANGD * sin(a));
            }
        }
        xl[(h * 2) * 360 + k]     = ar;
        xl[(h * 2 + 1) * 360 + k] = ai;
    }
    __syncthreads();

    for (int n = tid; n < 360; n += 256) {
        float accr[8], acci[8];
#pragma unroll
        for (int i = 0; i < 8; ++i) { accr[i] = 0.f; acci[i] = 0.f; }
        const size_t wbase = ((size_t)m * 360 + n) * 360;
        if (wbase + 360 <= (size_t)nw) {
            const float* wr = W + wbase;
            for (int k = 0; k < 360; ++k) {
                float w = wr[k];
#pragma unroll
                for (int h = 0; h < 8; ++h) {
                    accr[h] += w * xl[(h * 2) * 360 + k];
                    acci[h] += w * xl[(h * 2 + 1) * 360 + k];
                }
            }
        }
#pragma unroll
        for (int h = 0; h < 8; ++h) {
            size_t e = ((size_t)(h * 360) + n) * 361 + m;
            if (complexOut) {
                if (2 * e + 1 < (size_t)out_elems) {
                    out[2 * e]     = accr[h];
                    out[2 * e + 1] = acci[h];
                }
            } else {
                if (e < (size_t)out_elems) out[e] = accr[h];
            }
        }
    }
}

extern "C" void kernel_launch(void* const* d_in, const int* in_sizes, int n_in,
                              void* d_out, int out_size, void* d_ws, size_t ws_size,
                              hipStream_t stream) {
    if (n_in < 2) return;
    const float* x = (const float*)d_in[0];   // [1,8,360,720] float32
    const float* W = (const float*)d_in[1];   // [361,360,360] float32
    float* out = (float*)d_out;               // float32[out_size]; expected = Re(result)

    const long long nx = in_sizes[0];
    const long long nw = in_sizes[1];
    const long long out_elems = (long long)out_size;
    const bool complexOut = (out_elems >= 2LL * 1039680LL);
    const bool sizesOk = (nx >= 2073600LL) && (nw >= 46785600LL);

    int S = 0;
    for (int c = 4; c >= 1; c >>= 1) {
        size_t need = (TC_ELEMS + (size_t)c * P_STRIDE + OUTT_ELEMS) * sizeof(float);
        if (ws_size >= need) { S = c; break; }
    }

    if (!complexOut && sizesOk && S > 0 && d_ws != nullptr) {
        float* Tc = (float*)d_ws;
        float* P  = Tc + TC_ELEMS;
        float* oT = P + (size_t)S * P_STRIDE;
        tw_init_kernel<<<(int)((TC_ELEMS + 255) / 256), 256, 0, stream>>>(Tc);
        dft_re_kernel<<<dim3(3, 45, S), 256, 0, stream>>>(x, Tc, P, S);
        if (S > 1)
            reduce_kernel<<<(int)((P_STRIDE / 4 + 255) / 256), 256, 0, stream>>>(P, S);
        contract_re_kernel<<<dim3(12, 361), 128, 0, stream>>>(W, P, oT);
        transpose_kernel<<<dim3(12, 12, 8), dim3(32, 8), 0, stream>>>(oT, out, out_elems);
    } else {
        fused_kernel<<<dim3(361), 256, 0, stream>>>(x, W, out, nx, nw, out_elems,
                                                    complexOut ? 1 : 0);
    }
}